// Round 1
// baseline (635.854 us; speedup 1.0000x reference)
//
#include <hip/hip_runtime.h>
#include <math.h>

// Problem constants (from reference setup_inputs)
constexpr int B = 64;
constexpr int T = 1024;
constexpr int C = 128;
constexpr int L = 256;
constexpr int S = 2 * L + 1;  // 513 extended states
#define NEGF (-1e30f)

// Kernel 1: log_tm[t, b, c] = log(y_pred[b, t, c]).  float4-vectorized over c.
// Output-linear indexing => fully coalesced writes; reads are 512B-contiguous
// chunks per (b,t) pair (memory-bound either way, ~67 MB total traffic).
__global__ void log_transpose(const float4* __restrict__ in, float4* __restrict__ out) {
    int idx = blockIdx.x * blockDim.x + threadIdx.x;  // over T*B*C/4 = 2M
    int c4 = idx & (C / 4 - 1);   // 32 float4 per row
    int tb = idx >> 5;            // t*B + b
    int b  = tb & (B - 1);
    int t  = tb >> 6;             // B = 64
    float4 v = in[(b * T + t) * (C / 4) + c4];
    float4 r;
    r.x = logf(v.x); r.y = logf(v.y); r.z = logf(v.z); r.w = logf(v.w);
    out[idx] = r;
}

// Kernel 2: CTC forward recursion, one block per batch element.
// alpha double-buffered in LDS; lp row double-buffered + prefetched one step
// ahead; exactly one __syncthreads per time step.
__global__ __launch_bounds__(512) void ctc_fwd(const float* __restrict__ logp,   // [T,B,C]
                                               const int* __restrict__ yt,       // [B,L]
                                               const int* __restrict__ il_,      // [B]
                                               const int* __restrict__ ll_,      // [B]
                                               float* __restrict__ loss_b) {     // [B]
    const int b = blockIdx.x;
    const int tid = threadIdx.x;

    __shared__ float alpha[2][S + 3];   // 516 floats per buffer
    __shared__ float lp[2][C];

    int il = il_[b]; il = il < 1 ? 1 : (il > T ? T : il);
    int ll = ll_[b]; ll = ll < 1 ? 1 : (ll > L ? L : ll);

    // This thread owns state s = tid; thread 0 additionally owns s = 512
    // (even state => blank label, no skip).
    const int s = tid;
    const int lab = (s & 1) ? yt[b * L + (s >> 1)] : 0;
    const bool skip = (s & 1) && (s >= 3) && (lab != yt[b * L + (s >> 1) - 1]);

    // t = 0: stage lp row, init alpha0.
    if (tid < C) lp[0][tid] = logp[(0 * B + b) * C + tid];
    __syncthreads();
    alpha[0][s] = (s <= 1) ? lp[0][lab] : NEGF;
    if (tid == 0) alpha[0][S - 1] = NEGF;
    // Prefetch t = 1.
    if (tid < C && il > 1) lp[1][tid] = logp[(1 * B + b) * C + tid];
    __syncthreads();

    int cur = 0;
    for (int t = 1; t < il; ++t) {
        const int par = t & 1;
        // Prefetch row t+1 into the other lp buffer (its last readers were
        // in iteration t-1, fenced by the barrier at the end of that iter).
        if (tid < C && (t + 1) < il) lp[par ^ 1][tid] = logp[((t + 1) * B + b) * C + tid];

        // new[s] = logsumexp(a[s], a[s-1], skip ? a[s-2] : NEG) + lp[ext[s]]
        float a  = alpha[cur][s];
        float a1 = (s >= 1) ? alpha[cur][s - 1] : NEGF;
        float a2 = skip ? alpha[cur][s - 2] : NEGF;
        float m = fmaxf(fmaxf(a, a1), a2);
        float sum = __expf(a - m) + __expf(a1 - m) + __expf(a2 - m);
        alpha[cur ^ 1][s] = m + __logf(sum) + lp[par][lab];

        if (tid == 0) {  // state S-1 = 512, even/blank
            float aa  = alpha[cur][S - 1];
            float aa1 = alpha[cur][S - 2];
            float mm  = fmaxf(aa, aa1);
            float ss  = __expf(aa - mm) + __expf(aa1 - mm) + __expf(NEGF - mm);
            alpha[cur ^ 1][S - 1] = mm + __logf(ss) + lp[par][0];
        }
        cur ^= 1;
        __syncthreads();
    }

    if (tid == 0) {
        float e1 = alpha[cur][2 * ll - 1];
        float e2 = alpha[cur][2 * ll];
        float m = fmaxf(e1, e2);
        loss_b[b] = -(m + __logf(__expf(e1 - m) + __expf(e2 - m)));
    }
}

// Kernel 3: mean of the 64 per-batch losses -> d_out[T*B*C].
__global__ void reduce_loss(const float* __restrict__ loss_b, float* __restrict__ out) {
    float v = loss_b[threadIdx.x];  // 64 threads = 1 wave
    #pragma unroll
    for (int off = 32; off > 0; off >>= 1) v += __shfl_down(v, off);
    if (threadIdx.x == 0) out[0] = v * (1.0f / (float)B);
}

extern "C" void kernel_launch(void* const* d_in, const int* in_sizes, int n_in,
                              void* d_out, int out_size, void* d_ws, size_t ws_size,
                              hipStream_t stream) {
    const int*   y_true = (const int*)d_in[0];
    const float* y_pred = (const float*)d_in[1];
    const int*   in_len = (const int*)d_in[2];
    const int*   lb_len = (const int*)d_in[3];

    float* out_log  = (float*)d_out;                         // [T,B,C]
    float* out_loss = (float*)d_out + (size_t)T * B * C;     // scalar
    float* loss_b   = (float*)d_ws;                          // [B] scratch

    const int n4 = T * B * C / 4;
    log_transpose<<<(n4 + 255) / 256, 256, 0, stream>>>((const float4*)y_pred, (float4*)out_log);
    ctc_fwd<<<B, 512, 0, stream>>>(out_log, y_true, in_len, lb_len, loss_b);
    reduce_loss<<<1, 64, 0, stream>>>(loss_b, out_loss);
}

// Round 2
// 235.227 us; speedup vs baseline: 2.7031x; 2.7031x over previous
//
#include <hip/hip_runtime.h>
#include <math.h>

// Problem constants (from reference setup_inputs)
constexpr int B = 64;
constexpr int T = 1024;
constexpr int C = 128;
constexpr int L = 256;
constexpr int S = 2 * L + 1;     // 513 extended states
constexpr int TRB = 2048;        // transpose blocks (blockIdx >= B)
constexpr int N4 = T * B * C / 4;

// Fused kernel:
//   blocks [0, B)      : CTC forward, one 64-lane wave per batch element,
//                        alpha in registers (linear-prob domain, periodic
//                        max-rescale), NO barriers in the T-loop.
//   blocks [B, B+TRB)  : log + [B,T,C] -> [T,B,C] transpose (Output 0).
__global__ __launch_bounds__(64) void ctc_fused(
    const float* __restrict__ yp,    // [B,T,C] probabilities
    const int*   __restrict__ yt,    // [B,L]
    const int*   __restrict__ il_,   // [B]
    const int*   __restrict__ ll_,   // [B]
    float* __restrict__ out_log,     // [T,B,C]
    float* __restrict__ out_loss)    // scalar, pre-zeroed; atomic mean
{
    if (blockIdx.x >= B) {
        // ---- transpose + log path (memory-bound, runs on idle CUs) ----
        int gid = (blockIdx.x - B) * 64 + threadIdx.x;
        const float4* in4 = (const float4*)yp;
        float4* o4 = (float4*)out_log;
        for (int i = gid; i < N4; i += TRB * 64) {
            int c4 = i & 31;
            int tb = i >> 5;
            int bb = tb & 63;
            int tt = tb >> 6;
            float4 v = in4[(bb * T + tt) * 32 + c4];
            float4 r;
            r.x = __logf(v.x); r.y = __logf(v.y);
            r.z = __logf(v.z); r.w = __logf(v.w);
            o4[i] = r;
        }
        return;
    }

    // ---- CTC forward path ----
    const int b    = blockIdx.x;
    const int lane = threadIdx.x;

    __shared__ float2 lsh[2][64];   // 2-deep ring of probability rows (128 f32)
    __shared__ float  afin[S];      // final alphas for loss extraction

    int il = il_[b]; il = min(max(il, 1), T);
    int ll = ll_[b]; ll = min(max(ll, 1), L);

    const float* yb = yp + (size_t)b * T * C;   // [T,C] slice for this b

    // Labels: lane owns states s = 8*lane + j. Odd j -> label yt[4*lane + (j-1)/2].
    int4 y4 = *(const int4*)(yt + b * L + 4 * lane);
    int prevlab = (lane > 0) ? yt[b * L + 4 * lane - 1] : y4.x;
    float sk1 = (lane > 0 && y4.x != prevlab) ? 1.f : 0.f;
    float sk3 = (y4.y != y4.x) ? 1.f : 0.f;
    float sk5 = (y4.z != y4.y) ? 1.f : 0.f;
    float sk7 = (y4.w != y4.z) ? 1.f : 0.f;

    // Register ring: pr[r & 7] holds probability row r (float2 per lane).
    float2 pr[8];
    #pragma unroll
    for (int r = 0; r < 8; ++r) pr[r] = ((const float2*)(yb + r * C))[lane];

    // Stage row 0, init alpha (linear domain). alpha0: a[0]=p0[blank], a[1]=p0[lab1].
    lsh[0][lane] = pr[0];
    pr[0] = ((const float2*)(yb + 8 * C))[lane];
    {
        const float* l0 = (const float*)lsh[0];
        float gb0 = l0[0], g10 = l0[y4.x];
        float z = 0.f;
        if (lane == 0) { /* keep */ } else { gb0 = z; g10 = z; }
        // set below
        afin[0] = 0.f; // touch to keep afin alive (overwritten later)
        // alpha registers
        // (declared next; init here via locals)
        (void)gb0; (void)g10;
    }
    float a0 = 0.f, a1 = 0.f, a2 = 0.f, a3 = 0.f, a4 = 0.f,
          a5 = 0.f, a6 = 0.f, a7 = 0.f, a8 = 0.f;
    {
        const float* l0 = (const float*)lsh[0];
        if (lane == 0) { a0 = l0[0]; a1 = l0[y4.x]; }
    }

    // Stage row 1 and gather it (consumed at t=1).
    lsh[1][lane] = pr[1];
    pr[1] = ((const float2*)(yb + 9 * C))[lane];
    float gb, g1, g3, g5, g7;
    {
        const float* l1 = (const float*)lsh[1];
        gb = l1[0]; g1 = l1[y4.x]; g3 = l1[y4.y]; g5 = l1[y4.z]; g7 = l1[y4.w];
    }

    float ls = 0.f;   // accumulated log2 of rescale factors

    // One time step. u == t & 7 (compile-time at every inline site).
    auto step = [&](int t, int u) {
        bool act = (t < il);
        // Halo: alpha[s-1] for j=0 and alpha[s-2] for j=1 are both prev lane's a7.
        float h = __shfl_up(a7, 1);
        if (lane == 0) h = 0.f;
        float v0 = (a0 + h)              * gb;
        float v1 = (a1 + a0 + sk1 * h)   * g1;
        float v2 = (a2 + a1)             * gb;
        float v3 = (a3 + a2 + sk3 * a1)  * g3;
        float v4 = (a4 + a3)             * gb;
        float v5 = (a5 + a4 + sk5 * a3)  * g5;
        float v6 = (a6 + a5)             * gb;
        float v7 = (a7 + a6 + sk7 * a5)  * g7;
        float v8 = (a8 + a7)             * gb;   // state 512 (lane 63 only meaningful)
        if (act) { a0=v0; a1=v1; a2=v2; a3=v3; a4=v4; a5=v5; a6=v6; a7=v7; a8=v8; }

        // Stage row t+1 into LDS (its global load completed ~7 iters ago),
        // refill the register ring with row t+9, then gather row t+1 for the
        // next iteration (one full iteration of LDS-latency slack).
        int rs = (u + 1) & 7;
        int ps = (u + 1) & 1;
        lsh[ps][lane] = pr[rs];
        int nr = t + 9; if (nr > T - 1) nr = T - 1;
        pr[rs] = ((const float2*)(yb + nr * C))[lane];
        const float* l = (const float*)lsh[ps];
        gb = l[0]; g1 = l[y4.x]; g3 = l[y4.y]; g5 = l[y4.z]; g7 = l[y4.w];

        // Periodic max-rescale (keeps linear alphas in f32 range).
        if (u == 7 && act) {
            float m = fmaxf(fmaxf(fmaxf(a0, a1), fmaxf(a2, a3)),
                            fmaxf(fmaxf(a4, a5), fmaxf(a6, a7)));
            m = fmaxf(m, a8);
            #pragma unroll
            for (int off = 1; off < 64; off <<= 1)
                m = fmaxf(m, __shfl_xor(m, off));
            float inv = 1.0f / m;
            a0 *= inv; a1 *= inv; a2 *= inv; a3 *= inv; a4 *= inv;
            a5 *= inv; a6 *= inv; a7 *= inv; a8 *= inv;
            ls += __log2f(m);
        }
    };

    // t = 1..7 (il >= 1 clip; these are always < il in practice, `act` guards anyway)
    #pragma unroll
    for (int t = 1; t < 8; ++t) step(t, t);

    // Main loop, 8 steps per block; ring indices static via u.
    for (int tb = 8; tb < T; tb += 8) {
        if (tb >= il) break;
        #pragma unroll
        for (int u = 0; u < 8; ++u) step(tb + u, u);
    }

    // Loss: -ln(alpha[2ll-1] + alpha[2ll]) with accumulated scale.
    afin[8 * lane + 0] = a0; afin[8 * lane + 1] = a1;
    afin[8 * lane + 2] = a2; afin[8 * lane + 3] = a3;
    afin[8 * lane + 4] = a4; afin[8 * lane + 5] = a5;
    afin[8 * lane + 6] = a6; afin[8 * lane + 7] = a7;
    if (lane == 63) afin[512] = a8;
    __syncthreads();
    if (lane == 0) {
        float e1 = afin[2 * ll - 1];
        float e2 = afin[2 * ll];
        float sum = fmaxf(e1 + e2, 1e-37f);
        float loss = -(__log2f(sum) + ls) * 0.6931471805599453f;  // back to nats
        atomicAdd(out_loss, loss * (1.0f / (float)B));
    }
}

extern "C" void kernel_launch(void* const* d_in, const int* in_sizes, int n_in,
                              void* d_out, int out_size, void* d_ws, size_t ws_size,
                              hipStream_t stream) {
    const int*   y_true = (const int*)d_in[0];
    const float* y_pred = (const float*)d_in[1];
    const int*   in_len = (const int*)d_in[2];
    const int*   lb_len = (const int*)d_in[3];

    float* out_log  = (float*)d_out;                      // [T,B,C]
    float* out_loss = (float*)d_out + (size_t)T * B * C;  // scalar

    hipMemsetAsync(out_loss, 0, sizeof(float), stream);
    ctc_fused<<<B + TRB, 64, 0, stream>>>(y_pred, y_true, in_len, lb_len,
                                          out_log, out_loss);
}

// Round 3
// 204.964 us; speedup vs baseline: 3.1023x; 1.1476x over previous
//
#include <hip/hip_runtime.h>
#include <math.h>

// Problem constants (from reference setup_inputs)
constexpr int B = 64;
constexpr int T = 1024;
constexpr int C = 128;
constexpr int L = 256;
constexpr int S = 2 * L + 1;     // 513 extended states
constexpr int TRB = 2048;        // transpose blocks (blockIdx >= B)
constexpr int N4 = T * B * C / 4;

template <int N> struct IC { static constexpr int value = N; };

// Fused kernel:
//   blocks [0, B)      : CTC forward, one 64-lane wave per batch element.
//                        Linear-prob domain, alpha in registers, 4-step
//                        halo-blocked updates (halo = prev lane's 8 states via
//                        shfl_up once per 4 steps), two 4-row LDS ping-pong
//                        buffers with gathers pipelined one group ahead,
//                        rescale butterfly pipelined across 8-step bodies.
//   blocks [B, B+TRB)  : log + [B,T,C] -> [T,B,C] transpose (Output 0).
__global__ __launch_bounds__(64) void ctc_fused(
    const float* __restrict__ yp,    // [B,T,C] probabilities
    const int*   __restrict__ yt,    // [B,L]
    const int*   __restrict__ il_,   // [B]
    const int*   __restrict__ ll_,   // [B]
    float* __restrict__ out_log,     // [T,B,C]
    float* __restrict__ out_loss)    // scalar, pre-zeroed; atomic mean
{
    if (blockIdx.x >= B) {
        // ---- transpose + log path (memory-bound, runs on idle CUs) ----
        int gid = (blockIdx.x - B) * 64 + threadIdx.x;
        const float4* in4 = (const float4*)yp;
        float4* o4 = (float4*)out_log;
        for (int i = gid; i < N4; i += TRB * 64) {
            int c4 = i & 31;
            int tb = i >> 5;
            int bb = tb & 63;
            int tt = tb >> 6;
            float4 v = in4[(bb * T + tt) * 32 + c4];
            float4 r;
            r.x = __logf(v.x); r.y = __logf(v.y);
            r.z = __logf(v.z); r.w = __logf(v.w);
            o4[i] = r;
        }
        return;
    }

    // ---- CTC forward path ----
    const int b    = blockIdx.x;
    const int lane = threadIdx.x;

    __shared__ float lsh[1024];   // two 4-row buffers: buf q at [q*512, q*512+512)
    __shared__ float afin[S];     // final alphas for loss extraction

    int il = il_[b]; il = min(max(il, 1), T);
    int ll = ll_[b]; ll = min(max(ll, 1), L);
    const float* yb = yp + (size_t)b * T * C;   // [T,C] slice for this b

    // Labels. Lane owns states s = 8*lane-8+i for the work array w[i], i in [0,16];
    // persistent alphas live in w[8..16] (states 8l..8l+8), w[0..7] is the halo.
    int4 y4  = *(const int4*)(yt + b * L + 4 * lane);
    int  po  = lane ? 4 * lane - 4 : 0;
    int4 py4 = *(const int4*)(yt + b * L + po);              // prev lane's labels
    int  ppw = yt[b * L + (lane >= 2 ? 4 * lane - 5 : 0)];

    int lab[8]   = {py4.x, py4.y, py4.z, py4.w, y4.x, y4.y, y4.z, y4.w};
    int labm1[8] = {ppw,   py4.x, py4.y, py4.z, py4.w, y4.x, y4.y, y4.z};
    float skf[8];   // skip-allowed flag for odd state 8l-7+2k
    #pragma unroll
    for (int k = 0; k < 8; ++k)
        skf[k] = ((4 * lane + k >= 5) && (lab[k] != labm1[k])) ? 1.f : 0.f;

    // Static LDS gather addresses (float element index): buffer q, label k.
    int adr_lo[2][8], adr_hi[2][8];
    #pragma unroll
    for (int q = 0; q < 2; ++q)
        #pragma unroll
        for (int k = 0; k < 8; ++k) {
            adr_lo[q][k] = q * 512 + lab[k];          // rows 0,1 (ds_read2 pair)
            adr_hi[q][k] = q * 512 + lab[k] + 256;    // rows 2,3 (ds_read2 pair)
        }

    // ---- startup: global prefetch, stage rows, init alpha ----
    float2 prr[8], tmp[5];
    #pragma unroll
    for (int j = 0; j < 5; ++j) tmp[j] = ((const float2*)(yb + j * C))[lane];
    #pragma unroll
    for (int r = 5; r <= 12; ++r) prr[r & 7] = ((const float2*)(yb + r * C))[lane];

    ((float2*)(lsh + 512))[lane] = tmp[0];              // row 0 -> buf1 (temp)
    #pragma unroll
    for (int j = 1; j <= 4; ++j)
        ((float2*)(lsh + (j - 1) * 128))[lane] = tmp[j]; // rows 1..4 -> buf0

    float a0v = lsh[512];
    float a1v = lsh[512 + y4.x];

    float gvo[2][4][8], gvb[2][4];
    #pragma unroll
    for (int k = 0; k < 8; ++k) {
        gvo[0][0][k] = lsh[adr_lo[0][k]];
        gvo[0][1][k] = lsh[adr_lo[0][k] + 128];
        gvo[0][2][k] = lsh[adr_hi[0][k]];
        gvo[0][3][k] = lsh[adr_hi[0][k] + 128];
    }
    gvb[0][0] = lsh[0];   gvb[0][1] = lsh[128];
    gvb[0][2] = lsh[256]; gvb[0][3] = lsh[384];

    float w[17];
    #pragma unroll
    for (int i = 0; i < 17; ++i) w[i] = 0.f;
    if (lane == 0) { w[8] = a0v; w[9] = a1v; }   // alpha0: states 0,1

    auto halo = [&]() {
        #pragma unroll
        for (int k = 0; k < 8; ++k) {
            float h = __shfl_up(w[8 + k], 1);
            w[k] = lane ? h : 0.f;
        }
    };
    halo();

    int t0 = 0;
    // One 4-step group at phase P: rows t0+1..t0+4 (gv[P], pre-gathered),
    // stages rows t0+5..t0+8 into buffer P^1, gathers gv[P^1] for next group.
    auto group = [&](auto Pc) {
        constexpr int P = decltype(Pc)::value;
        #pragma unroll
        for (int j = 0; j < 4; ++j) {
            const int slot = (5 + 4 * P + j) & 7;     // pr ring slot = row & 7
            ((float2*)(lsh + (P ^ 1) * 512 + j * 128))[lane] = prr[slot];
            int rr = t0 + 13 + j; rr = rr > T - 1 ? T - 1 : rr;
            prr[slot] = ((const float2*)(yb + rr * C))[lane];
        }
        // gathers for next group (full group of latency slack)
        #pragma unroll
        for (int k = 0; k < 8; ++k) {
            gvo[P ^ 1][0][k] = lsh[adr_lo[P ^ 1][k]];
            gvo[P ^ 1][1][k] = lsh[adr_lo[P ^ 1][k] + 128];
            gvo[P ^ 1][2][k] = lsh[adr_hi[P ^ 1][k]];
            gvo[P ^ 1][3][k] = lsh[adr_hi[P ^ 1][k] + 128];
        }
        gvb[P ^ 1][0] = lsh[(P ^ 1) * 512 + 0];
        gvb[P ^ 1][1] = lsh[(P ^ 1) * 512 + 128];
        gvb[P ^ 1][2] = lsh[(P ^ 1) * 512 + 256];
        gvb[P ^ 1][3] = lsh[(P ^ 1) * 512 + 384];
        // 4 halo-blocked time steps, in-place descending (reads only i-1, i-2)
        #pragma unroll
        for (int j = 0; j < 4; ++j) {
            #pragma unroll
            for (int i = 16; i >= 2 * (j + 1); --i) {
                float acc = w[i] + w[i - 1];
                float g;
                if (i & 1) {
                    acc = fmaf(skf[(i - 1) >> 1], w[i - 2], acc);
                    g = gvo[P][j][(i - 1) >> 1];
                } else {
                    g = gvb[P][j];
                }
                w[i] = acc * g;
            }
        }
        t0 += 4;
    };

    float ls = 0.f;        // accumulated log2 scale
    float m_meas = 1.0f;   // pipelined rescale max (raw, pre-butterfly)
    const int full_end = ((il - 1) >> 2) << 2;

    while (t0 + 8 <= full_end) {
        float mm = m_meas;  // butterfly pipelined across the 8-step body
        mm = fmaxf(mm, __shfl_xor(mm, 1));
        mm = fmaxf(mm, __shfl_xor(mm, 2));
        mm = fmaxf(mm, __shfl_xor(mm, 4));
        group(IC<0>{});
        halo();
        mm = fmaxf(mm, __shfl_xor(mm, 8));
        mm = fmaxf(mm, __shfl_xor(mm, 16));
        mm = fmaxf(mm, __shfl_xor(mm, 32));
        group(IC<1>{});
        // exact power-of-2 rescale, centered at 2^32 for underflow headroom
        int eb = (__float_as_int(mm) >> 23) & 0xff;
        float inv = __int_as_float((286 - eb) << 23);   // 2^(159-eb)
        #pragma unroll
        for (int i = 8; i < 17; ++i) w[i] *= inv;
        ls += (float)(eb - 159);
        m_meas = fmaxf(fmaxf(fmaxf(w[8], w[9]), fmaxf(w[10], w[11])),
                       fmaxf(fmaxf(w[12], w[13]),
                             fmaxf(fmaxf(w[14], w[15]), w[16])));
        halo();
    }
    if (t0 + 4 <= full_end) group(IC<0>{});

    // tail: rows full_end+1 .. il-1 (0..3 steps), simple per-step path
    const int bufT = (full_end >> 2) & 1;
    for (int r = full_end + 1; r < il; ++r) {
        const float* rp = lsh + bufT * 512 + ((r - 1) & 3) * 128;
        float hh = __shfl_up(w[15], 1); if (lane == 0) hh = 0.f;
        float gb = rp[0];
        float n8  = (w[8] + hh) * gb;
        float n9  = fmaf(skf[4], hh,    w[9]  + w[8])  * rp[y4.x];
        float n10 = (w[10] + w[9])  * gb;
        float n11 = fmaf(skf[5], w[9],  w[11] + w[10]) * rp[y4.y];
        float n12 = (w[12] + w[11]) * gb;
        float n13 = fmaf(skf[6], w[11], w[13] + w[12]) * rp[y4.z];
        float n14 = (w[14] + w[13]) * gb;
        float n15 = fmaf(skf[7], w[13], w[15] + w[14]) * rp[y4.w];
        float n16 = (w[16] + w[15]) * gb;
        w[8] = n8;  w[9] = n9;  w[10] = n10; w[11] = n11; w[12] = n12;
        w[13] = n13; w[14] = n14; w[15] = n15; w[16] = n16;
    }

    // Loss: -ln(alpha[2ll-1] + alpha[2ll]) with accumulated scale.
    #pragma unroll
    for (int k = 0; k < 8; ++k) afin[8 * lane + k] = w[8 + k];
    if (lane == 63) afin[512] = w[16];
    __syncthreads();
    if (lane == 0) {
        float e1 = afin[2 * ll - 1];
        float e2 = afin[2 * ll];
        float sum = fmaxf(e1 + e2, 1e-37f);
        float loss = -(__log2f(sum) + ls) * 0.6931471805599453f;  // nats
        atomicAdd(out_loss, loss * (1.0f / (float)B));
    }
}

extern "C" void kernel_launch(void* const* d_in, const int* in_sizes, int n_in,
                              void* d_out, int out_size, void* d_ws, size_t ws_size,
                              hipStream_t stream) {
    const int*   y_true = (const int*)d_in[0];
    const float* y_pred = (const float*)d_in[1];
    const int*   in_len = (const int*)d_in[2];
    const int*   lb_len = (const int*)d_in[3];

    float* out_log  = (float*)d_out;                      // [T,B,C]
    float* out_loss = (float*)d_out + (size_t)T * B * C;  // scalar

    hipMemsetAsync(out_loss, 0, sizeof(float), stream);
    ctc_fused<<<B + TRB, 64, 0, stream>>>(y_pred, y_true, in_len, lb_len,
                                          out_log, out_loss);
}

// Round 4
// 198.147 us; speedup vs baseline: 3.2090x; 1.0344x over previous
//
#include <hip/hip_runtime.h>
#include <math.h>

// Problem constants (from reference setup_inputs)
constexpr int B = 64;
constexpr int T = 1024;
constexpr int C = 128;
constexpr int L = 256;
constexpr int S = 2 * L + 1;     // 513 extended states
constexpr int TRB = 2048;        // transpose blocks (blockIdx >= B)
constexpr int N4 = T * B * C / 4;

template <int N> struct IC { static constexpr int value = N; };

// Fused kernel:
//   blocks [0, B)      : CTC forward, one 64-lane wave per batch element.
//                        Linear-prob domain, alpha in registers, 4-step
//                        halo-blocked updates. Triple-buffered LDS rows,
//                        gathers issued one group ahead of use and BEFORE
//                        the staging writes (in-order DS pipe => no vmcnt
//                        coupling), float4 2-row staging with a 4-group-deep
//                        global prefetch ring. __launch_bounds__(64,1) so
//                        the ~150-reg state never spills (R3 ran at 60 VGPRs
//                        => scratch spills were the main stall).
//   blocks [B, B+TRB)  : log + [B,T,C] -> [T,B,C] transpose (Output 0).
__global__ __launch_bounds__(64, 1) void ctc_fused(
    const float* __restrict__ yp,    // [B,T,C] probabilities
    const int*   __restrict__ yt,    // [B,L]
    const int*   __restrict__ il_,   // [B]
    const int*   __restrict__ ll_,   // [B]
    float* __restrict__ out_log,     // [T,B,C]
    float* __restrict__ out_loss)    // scalar, pre-zeroed; atomic mean
{
    if (blockIdx.x >= B) {
        // ---- transpose + log path (memory-bound, runs on idle CUs) ----
        int gid = (blockIdx.x - B) * 64 + threadIdx.x;
        const float4* in4 = (const float4*)yp;
        float4* o4 = (float4*)out_log;
        for (int i = gid; i < N4; i += TRB * 64) {
            int c4 = i & 31;
            int tb = i >> 5;
            int bb = tb & 63;
            int tt = tb >> 6;
            float4 v = in4[(bb * T + tt) * 32 + c4];
            float4 r;
            r.x = __logf(v.x); r.y = __logf(v.y);
            r.z = __logf(v.z); r.w = __logf(v.w);
            o4[i] = r;
        }
        return;
    }

    // ---- CTC forward path ----
    const int b    = blockIdx.x;
    const int lane = threadIdx.x;

    __shared__ float lsh[1536];   // three 4-row buffers (512 floats each)
    __shared__ float afin[S];     // final alphas for loss extraction

    int il = il_[b]; il = min(max(il, 1), T);
    int ll = ll_[b]; ll = min(max(ll, 1), L);
    const float* yb = yp + (size_t)b * T * C;   // [T,C] slice for this b

    // Labels. Lane owns states s = 8*lane-8+i in w[i], i in [0,16];
    // persistent alphas in w[8..16] (states 8l..8l+8), w[0..7] is the halo.
    int4 y4  = *(const int4*)(yt + b * L + 4 * lane);
    int  po  = lane ? 4 * lane - 4 : 0;
    int4 py4 = *(const int4*)(yt + b * L + po);              // prev lane's labels
    int  ppw = yt[b * L + (lane >= 2 ? 4 * lane - 5 : 0)];

    int lab[8]   = {py4.x, py4.y, py4.z, py4.w, y4.x, y4.y, y4.z, y4.w};
    int labm1[8] = {ppw,   py4.x, py4.y, py4.z, py4.w, y4.x, y4.y, y4.z};
    float skf[8];
    #pragma unroll
    for (int k = 0; k < 8; ++k)
        skf[k] = ((4 * lane + k >= 5) && (lab[k] != labm1[k])) ? 1.f : 0.f;

    // Pair loader: pair m = rows (2m+1, 2m+2); lanes 0..31 carry the first
    // row, 32..63 the second; the wave reads 1KB fully coalesced.
    auto ldpair = [&](int m) -> float4 {
        int r = 2 * m + 1 + (lane >> 5);
        r = r > T - 1 ? T - 1 : r;
        return ((const float4*)(yb + r * C))[lane & 31];
    };

    // ---- warm-up: all global loads up front ----
    float p00 = yb[0];
    float p0l = yb[y4.x];
    float4 w01 = ldpair(0), w23 = ldpair(1);   // rows 1..4  -> buffer 0
    float4 w45 = ldpair(2), w67 = ldpair(3);   // rows 5..8  -> buffer 1
    float4 prr[8];                             // ring: pair m at slot m&7
    #pragma unroll
    for (int m = 4; m <= 11; ++m) prr[m & 7] = ldpair(m);   // rows 9..24

    ((float4*)(lsh +   0))[lane] = w01;
    ((float4*)(lsh + 256))[lane] = w23;
    ((float4*)(lsh + 512))[lane] = w45;
    ((float4*)(lsh + 768))[lane] = w67;

    int b_cur = 0, b_nxt = 512, b_stg = 1024;   // rotating buffer bases
    int t0 = 0;

    // Gather double-buffer (phase = group parity). k=0 is never consumed.
    float gvo[2][4][8], gvb[2][4];
    #pragma unroll
    for (int j = 0; j < 4; ++j) {               // warm-up gather: rows 1..4
        const float* rp = lsh + j * 128;
        gvb[0][j] = rp[0];
        #pragma unroll
        for (int k = 1; k < 8; ++k) gvo[0][j][k] = rp[lab[k]];
    }

    float w[17];
    #pragma unroll
    for (int i = 0; i < 17; ++i) w[i] = 0.f;
    if (lane == 0) { w[8] = p00; w[9] = p0l; }   // alpha0: states 0,1

    auto halo = [&]() {
        #pragma unroll
        for (int k = 0; k < 8; ++k) {
            float h = __shfl_up(w[8 + k], 1);
            w[k] = lane ? h : 0.f;
        }
    };
    halo();

    float ls = 0.f;        // accumulated log2 scale (exact integers)
    float m_meas = 1.0f;   // pipelined rescale max (lags ~8 steps)

    // One 4-step group, phase P, prr slot base S0 (compile-time).
    auto group = [&](auto Pc, auto S0c) {
        constexpr int P  = decltype(Pc)::value;
        constexpr int S0 = decltype(S0c)::value;
        // 1) gathers for the NEXT group (buffer staged one group ago; DS
        //    in-order per wave => data is there, no vmcnt dependence).
        #pragma unroll
        for (int j = 0; j < 4; ++j) {
            const float* rp = lsh + b_nxt + j * 128;
            gvb[P ^ 1][j] = rp[0];
            #pragma unroll
            for (int k = 1; k < 8; ++k) gvo[P ^ 1][j][k] = rp[lab[k]];
        }
        // 2) stage rows t0+9..t0+12 into b_stg (loads completed ~4 groups
        //    ago), refill the ring with rows t0+25..t0+28.
        ((float4*)(lsh + b_stg      ))[lane] = prr[S0];
        ((float4*)(lsh + b_stg + 256))[lane] = prr[S0 + 1];
        prr[S0]     = ldpair((t0 >> 1) + 12);
        prr[S0 + 1] = ldpair((t0 >> 1) + 13);
        // 3) wedge: 4 halo-blocked steps, in-place descending.
        #pragma unroll
        for (int j = 0; j < 4; ++j) {
            #pragma unroll
            for (int i = 16; i >= 2 * (j + 1); --i) {
                float acc = w[i] + w[i - 1];
                float g;
                if (i & 1) {
                    acc = fmaf(skf[(i - 1) >> 1], w[i - 2], acc);
                    g = gvo[P][j][(i - 1) >> 1];
                } else {
                    g = gvb[P][j];
                }
                w[i] = acc * g;
            }
        }
        int tb = b_cur; b_cur = b_nxt; b_nxt = b_stg; b_stg = tb;
        t0 += 4;
    };

    // Exact power-of-2 rescale, centered at 2^96 (wide underflow headroom,
    // still >2^25 of overflow margin vs the stale-max worst case).
    auto rescale = [&](float mm) {
        int eb = (__float_as_int(mm) >> 23) & 0xff;
        int sh = 350 - eb;
        sh = sh > 254 ? 254 : (sh < 1 ? 1 : sh);
        float inv = __int_as_float(sh << 23);
        #pragma unroll
        for (int i = 8; i < 17; ++i) w[i] *= inv;
        ls -= (float)(sh - 127);
    };
    auto maxw = [&]() {
        return fmaxf(fmaxf(fmaxf(w[8], w[9]), fmaxf(w[10], w[11])),
                     fmaxf(fmaxf(w[12], w[13]),
                           fmaxf(fmaxf(w[14], w[15]), w[16])));
    };

    const int full_end = ((il - 1) >> 2) << 2;

    // Main body: 4 groups (16 steps) per iteration; prr slots static.
    while (t0 + 16 <= full_end) {
        float mm = m_meas;   // butterfly pipelined across 2 groups
        mm = fmaxf(mm, __shfl_xor(mm, 1));
        mm = fmaxf(mm, __shfl_xor(mm, 2));
        mm = fmaxf(mm, __shfl_xor(mm, 4));
        group(IC<0>{}, IC<4>{});
        halo();
        mm = fmaxf(mm, __shfl_xor(mm, 8));
        mm = fmaxf(mm, __shfl_xor(mm, 16));
        mm = fmaxf(mm, __shfl_xor(mm, 32));
        group(IC<1>{}, IC<6>{});
        rescale(mm);
        m_meas = maxw();
        halo();

        float m2 = m_meas;
        m2 = fmaxf(m2, __shfl_xor(m2, 1));
        m2 = fmaxf(m2, __shfl_xor(m2, 2));
        m2 = fmaxf(m2, __shfl_xor(m2, 4));
        group(IC<0>{}, IC<0>{});
        halo();
        m2 = fmaxf(m2, __shfl_xor(m2, 8));
        m2 = fmaxf(m2, __shfl_xor(m2, 16));
        m2 = fmaxf(m2, __shfl_xor(m2, 32));
        group(IC<1>{}, IC<2>{});
        rescale(m2);
        m_meas = maxw();
        halo();
    }
    // Leftover groups (0..3); <=15 unrescaled steps is safe at 2^96 center.
    if (t0 + 4 <= full_end) { group(IC<0>{}, IC<4>{}); halo(); }
    if (t0 + 4 <= full_end) { group(IC<1>{}, IC<6>{}); halo(); }
    if (t0 + 4 <= full_end) { group(IC<0>{}, IC<0>{}); }

    // Tail: rows full_end+1 .. il-1 (0..3 steps) from buffer b_cur.
    for (int r = full_end + 1; r < il; ++r) {
        const float* rp = lsh + b_cur + ((r - 1) & 3) * 128;
        float hh = __shfl_up(w[15], 1); if (lane == 0) hh = 0.f;
        float gb = rp[0];
        float n8  = (w[8] + hh) * gb;
        float n9  = fmaf(skf[4], hh,    w[9]  + w[8])  * rp[y4.x];
        float n10 = (w[10] + w[9])  * gb;
        float n11 = fmaf(skf[5], w[9],  w[11] + w[10]) * rp[y4.y];
        float n12 = (w[12] + w[11]) * gb;
        float n13 = fmaf(skf[6], w[11], w[13] + w[12]) * rp[y4.z];
        float n14 = (w[14] + w[13]) * gb;
        float n15 = fmaf(skf[7], w[13], w[15] + w[14]) * rp[y4.w];
        float n16 = (w[16] + w[15]) * gb;
        w[8] = n8;  w[9] = n9;  w[10] = n10; w[11] = n11; w[12] = n12;
        w[13] = n13; w[14] = n14; w[15] = n15; w[16] = n16;
    }

    // Loss: -ln(alpha[2ll-1] + alpha[2ll]) with accumulated scale.
    #pragma unroll
    for (int k = 0; k < 8; ++k) afin[8 * lane + k] = w[8 + k];
    if (lane == 63) afin[512] = w[16];
    __syncthreads();
    if (lane == 0) {
        float e1 = afin[2 * ll - 1];
        float e2 = afin[2 * ll];
        float sum = fmaxf(e1 + e2, 1e-37f);
        float loss = -(__log2f(sum) + ls) * 0.6931471805599453f;  // nats
        atomicAdd(out_loss, loss * (1.0f / (float)B));
    }
}

extern "C" void kernel_launch(void* const* d_in, const int* in_sizes, int n_in,
                              void* d_out, int out_size, void* d_ws, size_t ws_size,
                              hipStream_t stream) {
    const int*   y_true = (const int*)d_in[0];
    const float* y_pred = (const float*)d_in[1];
    const int*   in_len = (const int*)d_in[2];
    const int*   lb_len = (const int*)d_in[3];

    float* out_log  = (float*)d_out;                      // [T,B,C]
    float* out_loss = (float*)d_out + (size_t)T * B * C;  // scalar

    hipMemsetAsync(out_loss, 0, sizeof(float), stream);
    ctc_fused<<<B + TRB, 64, 0, stream>>>(y_pred, y_true, in_len, lb_len,
                                          out_log, out_loss);
}